// Round 6
// baseline (1947.606 us; speedup 1.0000x reference)
//
#include <hip/hip_runtime.h>
#include <math.h>

#define L 8
#define D 512
#define DD (D*D)
#define P 128
#define H 8
#define HD 64
#define B 2
#define NS 4
#define S 384
#define BS (B*S)                     // 768
#define XN (BS*D)                    // 393216
#define SS ((size_t)S*S)             // 147456
#define BHSS ((size_t)B*H*S*S)       // 2359296
#define NBLK 512                     // persistent grid: 2 blocks/CU guaranteed (58KB LDS)

typedef short bf16x8 __attribute__((ext_vector_type(8)));
typedef float f32x4 __attribute__((ext_vector_type(4)));

__device__ __forceinline__ unsigned short f2b(float f) {
    unsigned u = __float_as_uint(f);
    unsigned r = (u + 0x7FFF + ((u >> 16) & 1)) >> 16;
    return (unsigned short)r;
}
__device__ __forceinline__ float b2f(unsigned short u) {
    return __uint_as_float(((unsigned)u) << 16);
}

// ================= lead-in kernels (one-time, memory-bound) =================

__global__ __launch_bounds__(256) void k_init(const float* __restrict__ msa,
                                              float* __restrict__ x,
                                              unsigned short* __restrict__ xb,
                                              float* __restrict__ part,
                                              unsigned* __restrict__ bar) {
    int idx = blockIdx.x * 256 + threadIdx.x;
    if (idx < XN) {
        int b = idx / (S * D);
        int rem = idx - b * (S * D);
        float v = msa[(size_t)b * NS * S * D + rem];
        x[idx] = v;
        xb[idx] = f2b(v);
    }
    if (idx < 8 * BS * 3) part[idx] = 0.f;
    if (idx == 0) { bar[0] = 0u; bar[1] = 0u; }
}

// weight prep: transpose+convert to bf16 [N][K]; z: 0-7 Wq, 8-15 Wk, 16-23 Wv, 24-31 Wo, 32 Wb1, 33 Wc1
__global__ __launch_bounds__(256) void k_prep(const float* __restrict__ Wq,
        const float* __restrict__ Wk, const float* __restrict__ Wv,
        const float* __restrict__ Wo, const float* __restrict__ Wb1,
        const float* __restrict__ Wc1, unsigned short* __restrict__ wt) {
    __shared__ float ts[64][65];
    const int z = blockIdx.z;
    const float* src; int N = 512;
    if (z < 8)       src = Wq + (size_t)z * DD;
    else if (z < 16) src = Wk + (size_t)(z - 8) * DD;
    else if (z < 24) src = Wv + (size_t)(z - 16) * DD;
    else if (z < 32) src = Wo + (size_t)(z - 24) * DD;
    else if (z == 32) src = Wb1;
    else { src = Wc1; N = 256; }
    unsigned short* dst = wt + (size_t)z * DD;

    const int n0 = blockIdx.x * 64, k0 = blockIdx.y * 64;
    if (n0 >= N) return;
    const int t = threadIdx.x;
    #pragma unroll
    for (int m = 0; m < 16; m++) {
        int f = t + m * 256;
        int r = f >> 6, c = f & 63;
        ts[r][c] = src[(size_t)(k0 + r) * N + n0 + c];
    }
    __syncthreads();
    #pragma unroll
    for (int m = 0; m < 4; m++) {
        int o4 = t + m * 256;
        int nr = o4 >> 4, k4 = o4 & 15;
        ushort4 pk;
        pk.x = f2b(ts[k4 * 4 + 0][nr]);
        pk.y = f2b(ts[k4 * 4 + 1][nr]);
        pk.z = f2b(ts[k4 * 4 + 2][nr]);
        pk.w = f2b(ts[k4 * 4 + 3][nr]);
        *(ushort4*)&dst[(size_t)(n0 + nr) * 512 + k0 + k4 * 4] = pk;
    }
}

// pair bias via MFMA: bias[l,b,h,i,j] bf16
__global__ __launch_bounds__(256) void k_biasm(const float* __restrict__ pair,
        const float* __restrict__ Wpb, const float* __restrict__ bpb,
        unsigned short* __restrict__ bias) {
    __shared__ unsigned short Ws[64][136];
    __shared__ unsigned short Ps[64][136];
    const int t = threadIdx.x;
    const int lane = t & 63, w = t >> 6;
    const int jt = blockIdx.x, i = blockIdx.y, b = blockIdx.z;

    #pragma unroll
    for (int m = 0; m < 8; m++) {
        int f = (t + m * 256) * 4;
        float4 wv = *(const float4*)&Wpb[f];
        int l = f >> 10, rem = f & 1023;
        int k = rem >> 3, h = rem & 7;
        int lh = (l << 3) | h;
        Ws[lh + 0][k] = f2b(wv.x);
        Ws[lh + 1][k] = f2b(wv.y);
        Ws[lh + 2][k] = f2b(wv.z);
        Ws[lh + 3][k] = f2b(wv.w);
    }
    const float* prow = pair + (((size_t)b * S + i) * S + jt * 64) * P;
    #pragma unroll
    for (int m = 0; m < 8; m++) {
        int f = (t + m * 256) * 4;
        int r = f >> 7, c = f & 127;
        float4 pv = *(const float4*)&prow[f];
        ushort4 u;
        u.x = f2b(pv.x); u.y = f2b(pv.y); u.z = f2b(pv.z); u.w = f2b(pv.w);
        *(ushort4*)&Ps[r][c] = u;
    }
    __syncthreads();

    f32x4 acc[4];
    #pragma unroll
    for (int mi = 0; mi < 4; mi++) { acc[mi][0] = 0.f; acc[mi][1] = 0.f; acc[mi][2] = 0.f; acc[mi][3] = 0.f; }
    #pragma unroll
    for (int ks = 0; ks < 4; ks++) {
        bf16x8 bv = *(const bf16x8*)&Ps[w * 16 + (lane & 15)][ks * 32 + (lane >> 4) * 8];
        #pragma unroll
        for (int mi = 0; mi < 4; mi++) {
            bf16x8 av = *(const bf16x8*)&Ws[mi * 16 + (lane & 15)][ks * 32 + (lane >> 4) * 8];
            acc[mi] = __builtin_amdgcn_mfma_f32_16x16x32_bf16(av, bv, acc[mi], 0, 0, 0);
        }
    }
    const int j = jt * 64 + w * 16 + (lane & 15);
    #pragma unroll
    for (int mi = 0; mi < 4; mi++)
        #pragma unroll
        for (int reg = 0; reg < 4; reg++) {
            int lh = mi * 16 + (lane >> 4) * 4 + reg;
            float v = acc[mi][reg] + bpb[lh];
            size_t plane = ((size_t)(lh >> 3) * B + b) * H + (lh & 7);
            bias[plane * SS + (size_t)i * S + j] = f2b(v);
        }
}

// ================= persistent mega-kernel =================

struct SMemGemm { unsigned short As[64][40]; unsigned short Bs[64][40]; };
struct SMemAttn {
    unsigned short qs[16][72];
    unsigned short ksh[64][72];
    unsigned short vsh[64][72];
    float scs[16][392];
    unsigned short pbs[16][392];
    float invs[16];
};
union SMem { SMemGemm g; SMemAttn a; };   // 58432 B -> exactly 2 blocks/CU

__device__ __forceinline__ void gridbar(unsigned* cnt, unsigned* gen) {
    __syncthreads();
    if (threadIdx.x == 0) {
        __threadfence();   // release this block's writes device-wide
        unsigned g = __hip_atomic_load(gen, __ATOMIC_RELAXED, __HIP_MEMORY_SCOPE_AGENT);
        unsigned v = __hip_atomic_fetch_add(cnt, 1u, __ATOMIC_ACQ_REL, __HIP_MEMORY_SCOPE_AGENT);
        if (v == NBLK - 1u) {
            __hip_atomic_store(cnt, 0u, __ATOMIC_RELAXED, __HIP_MEMORY_SCOPE_AGENT);
            __hip_atomic_fetch_add(gen, 1u, __ATOMIC_ACQ_REL, __HIP_MEMORY_SCOPE_AGENT);
        } else {
            while (__hip_atomic_load(gen, __ATOMIC_RELAXED, __HIP_MEMORY_SCOPE_AGENT) == g)
                __builtin_amdgcn_s_sleep(8);
        }
        __threadfence();   // acquire: invalidate caches so we see other blocks' writes
    }
    __syncthreads();
}

// shared 64x64x512 bf16 MFMA core (K-pipelined)
__device__ __forceinline__ void gemm_core(SMemGemm& g, const unsigned short* pa,
        const unsigned short* pb, f32x4 acc[4], int lane, int w, int sr, int scc) {
    int4 ra = *(const int4*)pa;
    int4 rb = *(const int4*)pb;
    for (int kt = 0; kt < 512; kt += 32) {
        *(int4*)&g.As[sr][scc] = ra;
        *(int4*)&g.Bs[sr][scc] = rb;
        __syncthreads();
        if (kt + 32 < 512) {
            ra = *(const int4*)(pa + kt + 32);
            rb = *(const int4*)(pb + kt + 32);
        }
        bf16x8 a = *(const bf16x8*)&g.As[w * 16 + (lane & 15)][(lane >> 4) * 8];
        #pragma unroll
        for (int nt = 0; nt < 4; nt++) {
            bf16x8 bb = *(const bf16x8*)&g.Bs[nt * 16 + (lane & 15)][(lane >> 4) * 8];
            acc[nt] = __builtin_amdgcn_mfma_f32_16x16x32_bf16(a, bb, acc[nt], 0, 0, 0);
        }
        __syncthreads();
    }
}

__device__ __forceinline__ void f_qkv(SMemGemm& g, int z, int r, int l,
        const unsigned short* xb, const unsigned short* wt,
        const float* bq, const float* bk, const float* bv,
        unsigned short* qbb, unsigned short* kbb, unsigned short* vtb) {
    const unsigned short* Wt = wt + (size_t)(z * 8 + l) * DD;
    const float* bias = (z == 0) ? bq + l * D : (z == 1) ? bk + l * D : bv + l * D;
    unsigned short* out = (z == 0) ? qbb : (z == 1) ? kbb : vtb;
    const int t = threadIdx.x, lane = t & 63, w = t >> 6;
    const int m0 = (r >> 3) * 64, n0 = (r & 7) * 64;
    const int sr = t >> 2, scc = (t & 3) * 8;
    f32x4 acc[4];
    #pragma unroll
    for (int nt = 0; nt < 4; nt++) { acc[nt][0] = 0.f; acc[nt][1] = 0.f; acc[nt][2] = 0.f; acc[nt][3] = 0.f; }
    gemm_core(g, &xb[(size_t)(m0 + sr) * 512 + scc], &Wt[(size_t)(n0 + sr) * 512 + scc],
              acc, lane, w, sr, scc);
    #pragma unroll
    for (int nt = 0; nt < 4; nt++)
        #pragma unroll
        for (int reg = 0; reg < 4; reg++) {
            int row = m0 + w * 16 + (lane >> 4) * 4 + reg;
            int col = n0 + nt * 16 + (lane & 15);
            int b = row / S, i = row - b * S;
            int h = col >> 6, d = col & 63;
            float v = acc[nt][reg] + bias[col];
            if (z < 2) out[(((size_t)b * H + h) * S + i) * HD + d] = f2b(v);
            else       out[(((size_t)b * H + h) * HD + d) * S + i] = f2b(v);
        }
}

__device__ __forceinline__ void f_wo(SMemGemm& g, int r, int l,
        const unsigned short* aob, const unsigned short* wt, const float* bo,
        float* x, unsigned short* xb) {
    const unsigned short* Wt = wt + (size_t)(24 + l) * DD;
    const int t = threadIdx.x, lane = t & 63, w = t >> 6;
    const int m0 = (r >> 3) * 64, n0 = (r & 7) * 64;
    const int sr = t >> 2, scc = (t & 3) * 8;
    f32x4 acc[4];
    #pragma unroll
    for (int nt = 0; nt < 4; nt++) { acc[nt][0] = 0.f; acc[nt][1] = 0.f; acc[nt][2] = 0.f; acc[nt][3] = 0.f; }
    gemm_core(g, &aob[(size_t)(m0 + sr) * 512 + scc], &Wt[(size_t)(n0 + sr) * 512 + scc],
              acc, lane, w, sr, scc);
    const float* bias = bo + l * D;
    #pragma unroll
    for (int nt = 0; nt < 4; nt++)
        #pragma unroll
        for (int reg = 0; reg < 4; reg++) {
            int row = m0 + w * 16 + (lane >> 4) * 4 + reg;
            int col = n0 + nt * 16 + (lane & 15);
            float v = acc[nt][reg] + bias[col] + x[(size_t)row * D + col];
            x[(size_t)row * D + col] = v;
            xb[(size_t)row * D + col] = f2b(v);
        }
}

__device__ __forceinline__ void f_wb1(SMemGemm& g, int r,
        const unsigned short* xb, const unsigned short* wt, const float* bb1,
        const float* Wb2g, float* part) {
    const unsigned short* Wt = wt + (size_t)32 * DD;
    const int t = threadIdx.x, lane = t & 63, w = t >> 6;
    const int m0 = (r >> 3) * 64, n0 = (r & 7) * 64;
    const int sr = t >> 2, scc = (t & 3) * 8;
    f32x4 acc[4];
    #pragma unroll
    for (int nt = 0; nt < 4; nt++) { acc[nt][0] = 0.f; acc[nt][1] = 0.f; acc[nt][2] = 0.f; acc[nt][3] = 0.f; }
    gemm_core(g, &xb[(size_t)(m0 + sr) * 512 + scc], &Wt[(size_t)(n0 + sr) * 512 + scc],
              acc, lane, w, sr, scc);
    float w2[4][3];
    #pragma unroll
    for (int nt = 0; nt < 4; nt++) {
        int col = n0 + nt * 16 + (lane & 15);
        w2[nt][0] = Wb2g[col * 6 + 0];
        w2[nt][1] = Wb2g[col * 6 + 1];
        w2[nt][2] = Wb2g[col * 6 + 2];
    }
    #pragma unroll
    for (int reg = 0; reg < 4; reg++) {
        float p0 = 0.f, p1 = 0.f, p2 = 0.f;
        #pragma unroll
        for (int nt = 0; nt < 4; nt++) {
            float v = fmaxf(acc[nt][reg] + bb1[n0 + nt * 16 + (lane & 15)], 0.f);
            p0 += v * w2[nt][0];
            p1 += v * w2[nt][1];
            p2 += v * w2[nt][2];
        }
        #pragma unroll
        for (int m = 1; m < 16; m <<= 1) {
            p0 += __shfl_xor(p0, m);
            p1 += __shfl_xor(p1, m);
            p2 += __shfl_xor(p2, m);
        }
        if ((lane & 15) == 0) {
            int row = m0 + w * 16 + (lane >> 4) * 4 + reg;
            float* pp = &part[((size_t)(r & 7) * BS + row) * 3];
            pp[0] += p0; pp[1] += p1; pp[2] += p2;
        }
    }
}

__device__ __forceinline__ void f_wc1(SMemGemm& g, int r,
        const unsigned short* xb, const unsigned short* wt, const float* bc1,
        float* hc) {
    const unsigned short* Wt = wt + (size_t)33 * DD;
    const int t = threadIdx.x, lane = t & 63, w = t >> 6;
    const int m0 = (r >> 2) * 64, n0 = (r & 3) * 64;
    const int sr = t >> 2, scc = (t & 3) * 8;
    f32x4 acc[4];
    #pragma unroll
    for (int nt = 0; nt < 4; nt++) { acc[nt][0] = 0.f; acc[nt][1] = 0.f; acc[nt][2] = 0.f; acc[nt][3] = 0.f; }
    gemm_core(g, &xb[(size_t)(m0 + sr) * 512 + scc], &Wt[(size_t)(n0 + sr) * 512 + scc],
              acc, lane, w, sr, scc);
    #pragma unroll
    for (int nt = 0; nt < 4; nt++)
        #pragma unroll
        for (int reg = 0; reg < 4; reg++) {
            int row = m0 + w * 16 + (lane >> 4) * 4 + reg;
            int col = n0 + nt * 16 + (lane & 15);
            hc[(size_t)row * 256 + col] = fmaxf(acc[nt][reg] + bc1[col], 0.f);
        }
}

__device__ __forceinline__ void f_attn(SMemAttn& a, int it, int l,
        const unsigned short* qb, const unsigned short* kb, const unsigned short* vt,
        const unsigned short* biasb, unsigned short* aob) {
    const int t = threadIdx.x, lane = t & 63, w = t >> 6;
    const int i0 = (it % 24) * 16;
    const int h = (it / 24) & 7, b = it / 192;
    const size_t bh = (size_t)b * H + h;
    const unsigned short* qp = qb + (bh * S + i0) * HD;
    const unsigned short* kp = kb + bh * S * HD;
    const unsigned short* vp = vt + bh * HD * S;
    const unsigned short* bp = biasb + (size_t)l * BHSS + bh * SS + (size_t)i0 * S;

    if (t < 128) {
        int r = t >> 3, c = (t & 7) * 8;
        *(int4*)&a.qs[r][c] = *(const int4*)&qp[r * HD + c];
    }
    #pragma unroll
    for (int m = 0; m < 3; m++) {
        int f = t + m * 256;
        int r = f / 48, c = (f % 48) * 8;
        *(int4*)&a.pbs[r][c] = *(const int4*)&bp[(size_t)r * S + c];
    }
    __syncthreads();

    bf16x8 qa0 = *(const bf16x8*)&a.qs[lane & 15][(lane >> 4) * 8];
    bf16x8 qa1 = *(const bf16x8*)&a.qs[lane & 15][32 + (lane >> 4) * 8];

    for (int jt = 0; jt < 6; jt++) {
        #pragma unroll
        for (int m = 0; m < 2; m++) {
            int g2 = t + m * 256;
            int r = g2 >> 3, c = (g2 & 7) * 8;
            *(int4*)&a.ksh[r][c] = *(const int4*)&kp[(size_t)(jt * 64 + r) * HD + c];
        }
        __syncthreads();
        f32x4 acc; acc[0] = 0.f; acc[1] = 0.f; acc[2] = 0.f; acc[3] = 0.f;
        bf16x8 kb0 = *(const bf16x8*)&a.ksh[w * 16 + (lane & 15)][(lane >> 4) * 8];
        bf16x8 kb1 = *(const bf16x8*)&a.ksh[w * 16 + (lane & 15)][32 + (lane >> 4) * 8];
        acc = __builtin_amdgcn_mfma_f32_16x16x32_bf16(qa0, kb0, acc, 0, 0, 0);
        acc = __builtin_amdgcn_mfma_f32_16x16x32_bf16(qa1, kb1, acc, 0, 0, 0);
        const int col = jt * 64 + w * 16 + (lane & 15);
        #pragma unroll
        for (int reg = 0; reg < 4; reg++) {
            int row = (lane >> 4) * 4 + reg;
            a.scs[row][col] = acc[reg] * 0.125f + b2f(a.pbs[row][col]);
        }
        __syncthreads();
    }

    const int i = t >> 4, sub = t & 15;
    float mx = -1e30f;
    #pragma unroll
    for (int m = 0; m < 24; m++) mx = fmaxf(mx, a.scs[i][sub + m * 16]);
    #pragma unroll
    for (int m = 1; m < 16; m <<= 1) mx = fmaxf(mx, __shfl_xor(mx, m));
    float pv_[24];
    float sum = 0.f;
    #pragma unroll
    for (int m = 0; m < 24; m++) {
        float p = __expf(a.scs[i][sub + m * 16] - mx);
        pv_[m] = p;
        sum += p;
    }
    #pragma unroll
    for (int m = 1; m < 16; m <<= 1) sum += __shfl_xor(sum, m);
    if (sub == 0) a.invs[i] = 1.f / sum;
    __syncthreads();
    #pragma unroll
    for (int m = 0; m < 24; m++) a.pbs[i][sub + m * 16] = f2b(pv_[m]);
    __syncthreads();

    f32x4 oacc; oacc[0] = 0.f; oacc[1] = 0.f; oacc[2] = 0.f; oacc[3] = 0.f;
    for (int jt = 0; jt < 6; jt++) {
        #pragma unroll
        for (int m = 0; m < 2; m++) {
            int g2 = t + m * 256;
            int r = g2 >> 3, c = (g2 & 7) * 8;
            *(int4*)&a.vsh[r][c] = *(const int4*)&vp[(size_t)r * S + jt * 64 + c];
        }
        __syncthreads();
        #pragma unroll
        for (int kk = 0; kk < 2; kk++) {
            bf16x8 pa = *(const bf16x8*)&a.pbs[lane & 15][jt * 64 + kk * 32 + (lane >> 4) * 8];
            bf16x8 bb = *(const bf16x8*)&a.vsh[w * 16 + (lane & 15)][kk * 32 + (lane >> 4) * 8];
            oacc = __builtin_amdgcn_mfma_f32_16x16x32_bf16(pa, bb, oacc, 0, 0, 0);
        }
        __syncthreads();
    }
    #pragma unroll
    for (int reg = 0; reg < 4; reg++) {
        int row = (lane >> 4) * 4 + reg;
        int d = w * 16 + (lane & 15);
        float v = oacc[reg] * a.invs[row];
        aob[((size_t)(b * S + i0 + row)) * D + h * HD + d] = f2b(v);
    }
}

__device__ __forceinline__ void f_conf(int it, const float* hc, const float* Wc2,
        const float* bc2, const float* part, const float* bb2, float* out) {
    const int wv = threadIdx.x >> 6, lane = threadIdx.x & 63;
    const int row = it * 4 + wv;
    const float* hr = hc + (size_t)row * 256;
    float p = 0.f;
    #pragma unroll
    for (int m = 0; m < 4; m++) p += hr[m * 64 + lane] * Wc2[m * 64 + lane];
    #pragma unroll
    for (int m = 32; m; m >>= 1) p += __shfl_xor(p, m);
    if (lane == 0) out[B * S * 3 + row] = 1.f / (1.f + __expf(-(p + bc2[0])));
    int ci = it * 12 + threadIdx.x;
    if (threadIdx.x < 12) {
        int r = ci / 3, c = ci - r * 3;
        float s = 8.f * bb2[c];
        #pragma unroll
        for (int nb = 0; nb < 8; nb++) s += part[((size_t)nb * BS + r) * 3 + c];
        out[ci] = s;
    }
}

__global__ __launch_bounds__(256, 2) void k_mega(
        float* x, unsigned short* xb,
        unsigned short* qbb, unsigned short* kbb, unsigned short* vtb,
        unsigned short* aob, float* hc, float* part,
        const unsigned short* wt, const unsigned short* biasb,
        const float* bq, const float* bk, const float* bv, const float* bo,
        const float* bb1, const float* Wb2, const float* bc1,
        const float* Wc2, const float* bc2, const float* bb2,
        float* out, unsigned* bar) {
    __shared__ SMem sm;
    unsigned* cnt = bar;
    unsigned* gen = bar + 1;
    const int blk = blockIdx.x;

    for (int l = 0; l < L; ++l) {
        // Phase A: QKV(l) 288 tiles + Wb1(l-1) 96 tiles (both read current xb)
        const int nA = (l == 0) ? 288 : 384;
        for (int it = blk; it < nA; it += NBLK) {
            if (it < 288) f_qkv(sm.g, it / 96, it % 96, l, xb, wt, bq, bk, bv, qbb, kbb, vtb);
            else          f_wb1(sm.g, it - 288, xb, wt, bb1, Wb2, part);
        }
        gridbar(cnt, gen);
        // Phase B: attention 384 items
        for (int it = blk; it < 384; it += NBLK)
            f_attn(sm.a, it, l, qbb, kbb, vtb, biasb, aob);
        gridbar(cnt, gen);
        // Phase C: Wo + residual 96 tiles
        for (int it = blk; it < 96; it += NBLK)
            f_wo(sm.g, it, l, aob, wt, bo, x, xb);
        gridbar(cnt, gen);
    }
    // Final: Wb1(L-1) 96 + Wc1 48
    for (int it = blk; it < 144; it += NBLK) {
        if (it < 96) f_wb1(sm.g, it, xb, wt, bb1, Wb2, part);
        else         f_wc1(sm.g, it - 96, xb, wt, bc1, hc);
    }
    gridbar(cnt, gen);
    // Confidence + coords assembly: 192 items
    for (int it = blk; it < 192; it += NBLK)
        f_conf(it, hc, Wc2, bc2, part, bb2, out);
}

extern "C" void kernel_launch(void* const* d_in, const int* in_sizes, int n_in,
                              void* d_out, int out_size, void* d_ws, size_t ws_size,
                              hipStream_t stream) {
    const float* msa = (const float*)d_in[0];
    const float* pair = (const float*)d_in[1];
    const float* Wq = (const float*)d_in[2];
    const float* bq = (const float*)d_in[3];
    const float* Wk = (const float*)d_in[4];
    const float* bk = (const float*)d_in[5];
    const float* Wv = (const float*)d_in[6];
    const float* bv = (const float*)d_in[7];
    const float* Wpb = (const float*)d_in[8];
    const float* bpb = (const float*)d_in[9];
    const float* Wo = (const float*)d_in[10];
    const float* bo = (const float*)d_in[11];
    const float* Wb1 = (const float*)d_in[12];
    const float* bb1 = (const float*)d_in[13];
    const float* Wb2 = (const float*)d_in[14];
    const float* bb2 = (const float*)d_in[15];
    const float* Wc1 = (const float*)d_in[16];
    const float* bc1 = (const float*)d_in[17];
    const float* Wc2 = (const float*)d_in[18];
    const float* bc2 = (const float*)d_in[19];

    char* base = (char*)d_ws;
    float* x    = (float*)base;            base += (size_t)XN * 4;
    float* hc   = (float*)base;            base += (size_t)BS * 256 * 4;
    float* part = (float*)base;            base += (size_t)8 * BS * 3 * 4;
    unsigned* bar = (unsigned*)base;       base += 256;
    unsigned short* xb  = (unsigned short*)base;  base += (size_t)XN * 2;
    unsigned short* aob = (unsigned short*)base;  base += (size_t)XN * 2;
    unsigned short* qbb = (unsigned short*)base;  base += (size_t)XN * 2;
    unsigned short* kbb = (unsigned short*)base;  base += (size_t)XN * 2;
    unsigned short* vtb = (unsigned short*)base;  base += (size_t)XN * 2;
    unsigned short* wt  = (unsigned short*)base;  base += (size_t)34 * DD * 2;
    unsigned short* biasb = (unsigned short*)base;

    k_prep<<<dim3(8, 8, 34), 256, 0, stream>>>(Wq, Wk, Wv, Wo, Wb1, Wc1, wt);
    k_init<<<dim3(1536), 256, 0, stream>>>(msa, x, xb, part, bar);
    k_biasm<<<dim3(6, S, B), 256, 0, stream>>>(pair, Wpb, bpb, biasb);
    k_mega<<<dim3(NBLK), 256, 0, stream>>>(x, xb, qbb, kbb, vtb, aob, hc, part,
        wt, biasb, bq, bk, bv, bo, bb1, Wb2, bc1, Wc2, bc2, bb2,
        (float*)d_out, bar);
}

// Round 7
// 267.609 us; speedup vs baseline: 7.2778x; 7.2778x over previous
//
#include <hip/hip_runtime.h>
#include <math.h>

#define L 8
#define D 512
#define DD (D*D)
#define P 128
#define H 8
#define HD 64
#define B 2
#define NS 4
#define S 384
#define BS (B*S)                     // 768
#define XN (BS*D)                    // 393216
#define SS ((size_t)S*S)             // 147456
#define BHSS ((size_t)B*H*S*S)       // 2359296
#define NSLAB 32                     // part slabs: 16 n-blocks x 2 wc

typedef short bf16x8 __attribute__((ext_vector_type(8)));
typedef float f32x4 __attribute__((ext_vector_type(4)));

__device__ __forceinline__ unsigned short f2b(float f) {
    unsigned u = __float_as_uint(f);
    unsigned r = (u + 0x7FFF + ((u >> 16) & 1)) >> 16;
    return (unsigned short)r;
}
__device__ __forceinline__ float b2f(unsigned short u) {
    return __uint_as_float(((unsigned)u) << 16);
}

// ---------------- init: x = msa[:,0] (f32 + bf16), part = 0 ----------------
__global__ __launch_bounds__(256) void k_init(const float* __restrict__ msa,
                                              float* __restrict__ x,
                                              unsigned short* __restrict__ xb,
                                              float* __restrict__ part) {
    int idx = blockIdx.x * 256 + threadIdx.x;
    if (idx < XN) {
        int b = idx / (S * D);
        int rem = idx - b * (S * D);
        float v = msa[(size_t)b * NS * S * D + rem];
        x[idx] = v;
        xb[idx] = f2b(v);
    }
    if (idx < NSLAB * BS * 3) part[idx] = 0.f;
}

// ---------------- weight prep: transpose+convert to bf16 [N][K] ----------------
// z: 0-7 Wq[l], 8-15 Wk, 16-23 Wv, 24-31 Wo, 32 Wb1, 33 Wc1 (N=256)
__global__ __launch_bounds__(256) void k_prep(const float* __restrict__ Wq,
        const float* __restrict__ Wk, const float* __restrict__ Wv,
        const float* __restrict__ Wo, const float* __restrict__ Wb1,
        const float* __restrict__ Wc1, unsigned short* __restrict__ wt) {
    __shared__ float ts[64][65];
    const int z = blockIdx.z;
    const float* src; int N = 512;
    if (z < 8)       src = Wq + (size_t)z * DD;
    else if (z < 16) src = Wk + (size_t)(z - 8) * DD;
    else if (z < 24) src = Wv + (size_t)(z - 16) * DD;
    else if (z < 32) src = Wo + (size_t)(z - 24) * DD;
    else if (z == 32) src = Wb1;
    else { src = Wc1; N = 256; }
    unsigned short* dst = wt + (size_t)z * DD;

    const int n0 = blockIdx.x * 64, k0 = blockIdx.y * 64;
    if (n0 >= N) return;
    const int t = threadIdx.x;
    #pragma unroll
    for (int m = 0; m < 16; m++) {
        int f = t + m * 256;
        int r = f >> 6, c = f & 63;
        ts[r][c] = src[(size_t)(k0 + r) * N + n0 + c];
    }
    __syncthreads();
    #pragma unroll
    for (int m = 0; m < 4; m++) {
        int o4 = t + m * 256;
        int nr = o4 >> 4, k4 = o4 & 15;
        ushort4 pk;
        pk.x = f2b(ts[k4 * 4 + 0][nr]);
        pk.y = f2b(ts[k4 * 4 + 1][nr]);
        pk.z = f2b(ts[k4 * 4 + 2][nr]);
        pk.w = f2b(ts[k4 * 4 + 3][nr]);
        *(ushort4*)&dst[(size_t)(n0 + nr) * 512 + k0 + k4 * 4] = pk;
    }
}

// ---------------- pair bias via MFMA: bias[l,b,h,i,j] (bf16 out) ----------------
__global__ __launch_bounds__(256) void k_biasm(const float* __restrict__ pair,
        const float* __restrict__ Wpb, const float* __restrict__ bpb,
        unsigned short* __restrict__ bias) {
    __shared__ unsigned short Ws[64][136];
    __shared__ unsigned short Ps[64][136];
    const int t = threadIdx.x;
    const int lane = t & 63, w = t >> 6;
    const int jt = blockIdx.x, i = blockIdx.y, b = blockIdx.z;

    #pragma unroll
    for (int m = 0; m < 8; m++) {
        int f = (t + m * 256) * 4;
        float4 wv = *(const float4*)&Wpb[f];
        int l = f >> 10, rem = f & 1023;
        int k = rem >> 3, h = rem & 7;
        int lh = (l << 3) | h;
        Ws[lh + 0][k] = f2b(wv.x);
        Ws[lh + 1][k] = f2b(wv.y);
        Ws[lh + 2][k] = f2b(wv.z);
        Ws[lh + 3][k] = f2b(wv.w);
    }
    const float* prow = pair + (((size_t)b * S + i) * S + jt * 64) * P;
    #pragma unroll
    for (int m = 0; m < 8; m++) {
        int f = (t + m * 256) * 4;
        int r = f >> 7, c = f & 127;
        float4 pv = *(const float4*)&prow[f];
        ushort4 u;
        u.x = f2b(pv.x); u.y = f2b(pv.y); u.z = f2b(pv.z); u.w = f2b(pv.w);
        *(ushort4*)&Ps[r][c] = u;
    }
    __syncthreads();

    f32x4 acc[4];
    #pragma unroll
    for (int mi = 0; mi < 4; mi++) { acc[mi][0] = 0.f; acc[mi][1] = 0.f; acc[mi][2] = 0.f; acc[mi][3] = 0.f; }
    #pragma unroll
    for (int ks = 0; ks < 4; ks++) {
        bf16x8 bv = *(const bf16x8*)&Ps[w * 16 + (lane & 15)][ks * 32 + (lane >> 4) * 8];
        #pragma unroll
        for (int mi = 0; mi < 4; mi++) {
            bf16x8 av = *(const bf16x8*)&Ws[mi * 16 + (lane & 15)][ks * 32 + (lane >> 4) * 8];
            acc[mi] = __builtin_amdgcn_mfma_f32_16x16x32_bf16(av, bv, acc[mi], 0, 0, 0);
        }
    }
    const int j = jt * 64 + w * 16 + (lane & 15);
    #pragma unroll
    for (int mi = 0; mi < 4; mi++)
        #pragma unroll
        for (int reg = 0; reg < 4; reg++) {
            int lh = mi * 16 + (lane >> 4) * 4 + reg;
            float v = acc[mi][reg] + bpb[lh];
            size_t plane = ((size_t)(lh >> 3) * B + b) * H + (lh & 7);
            bias[plane * SS + (size_t)i * S + j] = f2b(v);
        }
}

// ================= 32x32-tile GEMM core (K=512, K-step 64) =================
// per wave: one 16x16 output tile; wr=row-half, wc=col-half
#define GEMM32_CORE(Abase, Wbase)                                              \
    f32x4 acc; acc[0] = 0.f; acc[1] = 0.f; acc[2] = 0.f; acc[3] = 0.f;         \
    {                                                                          \
        const unsigned short* pa = &(Abase)[(size_t)(m0 + sr) * 512 + scc];    \
        const unsigned short* pb = &(Wbase)[(size_t)(n0 + sr) * 512 + scc];    \
        int4 ra = *(const int4*)pa;                                            \
        int4 rb = *(const int4*)pb;                                            \
        for (int kt = 0; kt < 512; kt += 64) {                                 \
            *(int4*)&As[sr][scc] = ra;                                         \
            *(int4*)&Bs[sr][scc] = rb;                                         \
            __syncthreads();                                                   \
            if (kt + 64 < 512) {                                               \
                ra = *(const int4*)(pa + kt + 64);                             \
                rb = *(const int4*)(pb + kt + 64);                             \
            }                                                                  \
            _Pragma("unroll")                                                  \
            for (int kk = 0; kk < 2; kk++) {                                   \
                bf16x8 a = *(const bf16x8*)&As[wr * 16 + (lane & 15)][kk * 32 + (lane >> 4) * 8]; \
                bf16x8 bb = *(const bf16x8*)&Bs[wc * 16 + (lane & 15)][kk * 32 + (lane >> 4) * 8]; \
                acc = __builtin_amdgcn_mfma_f32_16x16x32_bf16(a, bb, acc, 0, 0, 0); \
            }                                                                  \
            __syncthreads();                                                   \
        }                                                                      \
    }

// ---------------- phase A: z=0,1,2 -> Q,K,V projections; z=3 -> Wb1(prev layer) ----------------
__global__ __launch_bounds__(256) void k_phaseA(const unsigned short* __restrict__ xb,
        const unsigned short* __restrict__ wt,
        const float* __restrict__ bq, const float* __restrict__ bk, const float* __restrict__ bv,
        unsigned short* __restrict__ qbb, unsigned short* __restrict__ kbb,
        unsigned short* __restrict__ vtb,
        const float* __restrict__ bb1, const float* __restrict__ Wb2g,
        float* __restrict__ part, int l) {
    __shared__ unsigned short As[32][72];
    __shared__ unsigned short Bs[32][72];
    const int t = threadIdx.x, lane = t & 63;
    const int w = t >> 6, wr = w >> 1, wc = w & 1;
    const int z = blockIdx.z;
    const int m0 = blockIdx.y * 32, n0 = blockIdx.x * 32;
    const int sr = t >> 3, scc = (t & 7) * 8;

    const unsigned short* Wt;
    const float* bias;
    if (z == 0)      { Wt = wt + (size_t)l * DD;        bias = bq + l * D; }
    else if (z == 1) { Wt = wt + (size_t)(8 + l) * DD;  bias = bk + l * D; }
    else if (z == 2) { Wt = wt + (size_t)(16 + l) * DD; bias = bv + l * D; }
    else             { Wt = wt + (size_t)32 * DD;       bias = bb1; }

    GEMM32_CORE(xb, Wt)

    const int col = n0 + wc * 16 + (lane & 15);
    const float bcol = bias[col];
    if (z < 3) {
        unsigned short* out = (z == 0) ? qbb : (z == 1) ? kbb : vtb;
        const int h = col >> 6, d = col & 63;
        #pragma unroll
        for (int reg = 0; reg < 4; reg++) {
            int row = m0 + wr * 16 + (lane >> 4) * 4 + reg;
            int b = row / S, i = row - b * S;
            float v = acc[reg] + bcol;
            if (z < 2) out[(((size_t)b * H + h) * S + i) * HD + d] = f2b(v);
            else       out[(((size_t)b * H + h) * HD + d) * S + i] = f2b(v);
        }
    } else {
        const float w20 = Wb2g[col * 6 + 0];
        const float w21 = Wb2g[col * 6 + 1];
        const float w22 = Wb2g[col * 6 + 2];
        #pragma unroll
        for (int reg = 0; reg < 4; reg++) {
            float v = fmaxf(acc[reg] + bcol, 0.f);
            float p0 = v * w20, p1 = v * w21, p2 = v * w22;
            #pragma unroll
            for (int m = 1; m < 16; m <<= 1) {
                p0 += __shfl_xor(p0, m);
                p1 += __shfl_xor(p1, m);
                p2 += __shfl_xor(p2, m);
            }
            if ((lane & 15) == 0) {
                int row = m0 + wr * 16 + (lane >> 4) * 4 + reg;
                float* pp = &part[((size_t)(blockIdx.x * 2 + wc) * BS + row) * 3];
                pp[0] += p0; pp[1] += p1; pp[2] += p2;
            }
        }
    }
}

// ---------------- Wo GEMM + residual -> x (f32) and xb (bf16) ----------------
__global__ __launch_bounds__(256) void k_wo(const unsigned short* __restrict__ aob,
        const unsigned short* __restrict__ wt, const float* __restrict__ bo,
        float* __restrict__ x, unsigned short* __restrict__ xb, int l) {
    __shared__ unsigned short As[32][72];
    __shared__ unsigned short Bs[32][72];
    const int t = threadIdx.x, lane = t & 63;
    const int w = t >> 6, wr = w >> 1, wc = w & 1;
    const int m0 = blockIdx.y * 32, n0 = blockIdx.x * 32;
    const int sr = t >> 3, scc = (t & 7) * 8;
    const unsigned short* Wt = wt + (size_t)(24 + l) * DD;

    GEMM32_CORE(aob, Wt)

    const int col = n0 + wc * 16 + (lane & 15);
    const float bcol = bo[l * D + col];
    #pragma unroll
    for (int reg = 0; reg < 4; reg++) {
        int row = m0 + wr * 16 + (lane >> 4) * 4 + reg;
        float v = acc[reg] + bcol + x[(size_t)row * D + col];
        x[(size_t)row * D + col] = v;
        xb[(size_t)row * D + col] = f2b(v);
    }
}

// ---------------- final: z=0 -> Wb1(L-1) coords partial; z=1 -> Wc1 relu -> hc ----------------
__global__ __launch_bounds__(256) void k_final(const unsigned short* __restrict__ xb,
        const unsigned short* __restrict__ wt,
        const float* __restrict__ bb1, const float* __restrict__ Wb2g, float* __restrict__ part,
        const float* __restrict__ bc1, float* __restrict__ hc) {
    __shared__ unsigned short As[32][72];
    __shared__ unsigned short Bs[32][72];
    const int t = threadIdx.x, lane = t & 63;
    const int w = t >> 6, wr = w >> 1, wc = w & 1;
    const int z = blockIdx.z;
    if (z == 1 && blockIdx.x >= 8) return;
    const int m0 = blockIdx.y * 32, n0 = blockIdx.x * 32;
    const int sr = t >> 3, scc = (t & 7) * 8;
    const unsigned short* Wt = (z == 0) ? wt + (size_t)32 * DD : wt + (size_t)33 * DD;

    GEMM32_CORE(xb, Wt)

    const int col = n0 + wc * 16 + (lane & 15);
    if (z == 0) {
        const float bcol = bb1[col];
        const float w20 = Wb2g[col * 6 + 0];
        const float w21 = Wb2g[col * 6 + 1];
        const float w22 = Wb2g[col * 6 + 2];
        #pragma unroll
        for (int reg = 0; reg < 4; reg++) {
            float v = fmaxf(acc[reg] + bcol, 0.f);
            float p0 = v * w20, p1 = v * w21, p2 = v * w22;
            #pragma unroll
            for (int m = 1; m < 16; m <<= 1) {
                p0 += __shfl_xor(p0, m);
                p1 += __shfl_xor(p1, m);
                p2 += __shfl_xor(p2, m);
            }
            if ((lane & 15) == 0) {
                int row = m0 + wr * 16 + (lane >> 4) * 4 + reg;
                float* pp = &part[((size_t)(blockIdx.x * 2 + wc) * BS + row) * 3];
                pp[0] += p0; pp[1] += p1; pp[2] += p2;
            }
        }
    } else {
        const float bcol = bc1[col];
        #pragma unroll
        for (int reg = 0; reg < 4; reg++) {
            int row = m0 + wr * 16 + (lane >> 4) * 4 + reg;
            hc[(size_t)row * 256 + col] = fmaxf(acc[reg] + bcol, 0.f);
        }
    }
}

// ---------------- MFMA flash attention: bf16 in/out ----------------
__global__ __launch_bounds__(256) void k_attnm(const unsigned short* __restrict__ qb,
        const unsigned short* __restrict__ kb, const unsigned short* __restrict__ vt,
        const unsigned short* __restrict__ biasL, unsigned short* __restrict__ aob) {
    __shared__ unsigned short qs[16][72];
    __shared__ unsigned short kvsh[64][72];     // K tiles (QK^T), then V tiles (PV)
    __shared__ float scs[16][392];
    __shared__ unsigned short pbs[16][392];
    __shared__ float invs[16];

    const int t = threadIdx.x, lane = t & 63, w = t >> 6;
    const int i0 = blockIdx.x * 16;
    const int h = blockIdx.y, b = blockIdx.z;
    const size_t bh = (size_t)b * H + h;
    const unsigned short* qp = qb + (bh * S + i0) * HD;
    const unsigned short* kp = kb + bh * S * HD;
    const unsigned short* vp = vt + bh * HD * S;
    const unsigned short* bp = biasL + bh * SS + (size_t)i0 * S;

    if (t < 128) {
        int r = t >> 3, c = (t & 7) * 8;
        *(int4*)&qs[r][c] = *(const int4*)&qp[r * HD + c];
    }
    #pragma unroll
    for (int m = 0; m < 3; m++) {
        int f = t + m * 256;
        int r = f / 48, c = (f % 48) * 8;
        *(int4*)&pbs[r][c] = *(const int4*)&bp[(size_t)r * S + c];
    }
    __syncthreads();

    bf16x8 qa0 = *(const bf16x8*)&qs[lane & 15][(lane >> 4) * 8];
    bf16x8 qa1 = *(const bf16x8*)&qs[lane & 15][32 + (lane >> 4) * 8];

    for (int jt = 0; jt < 6; jt++) {
        #pragma unroll
        for (int m = 0; m < 2; m++) {
            int g2 = t + m * 256;
            int r = g2 >> 3, c = (g2 & 7) * 8;
            *(int4*)&kvsh[r][c] = *(const int4*)&kp[(size_t)(jt * 64 + r) * HD + c];
        }
        __syncthreads();
        f32x4 acc; acc[0] = 0.f; acc[1] = 0.f; acc[2] = 0.f; acc[3] = 0.f;
        bf16x8 kb0 = *(const bf16x8*)&kvsh[w * 16 + (lane & 15)][(lane >> 4) * 8];
        bf16x8 kb1 = *(const bf16x8*)&kvsh[w * 16 + (lane & 15)][32 + (lane >> 4) * 8];
        acc = __builtin_amdgcn_mfma_f32_16x16x32_bf16(qa0, kb0, acc, 0, 0, 0);
        acc = __builtin_amdgcn_mfma_f32_16x16x32_bf16(qa1, kb1, acc, 0, 0, 0);
        const int col = jt * 64 + w * 16 + (lane & 15);
        #pragma unroll
        for (int reg = 0; reg < 4; reg++) {
            int row = (lane >> 4) * 4 + reg;
            scs[row][col] = acc[reg] * 0.125f + b2f(pbs[row][col]);
        }
        __syncthreads();
    }

    const int i = t >> 4, sub = t & 15;
    float mx = -1e30f;
    #pragma unroll
    for (int m = 0; m < 24; m++) mx = fmaxf(mx, scs[i][sub + m * 16]);
    #pragma unroll
    for (int m = 1; m < 16; m <<= 1) mx = fmaxf(mx, __shfl_xor(mx, m));
    float pv_[24];
    float sum = 0.f;
    #pragma unroll
    for (int m = 0; m < 24; m++) {
        float p = __expf(scs[i][sub + m * 16] - mx);
        pv_[m] = p;
        sum += p;
    }
    #pragma unroll
    for (int m = 1; m < 16; m <<= 1) sum += __shfl_xor(sum, m);
    if (sub == 0) invs[i] = 1.f / sum;
    __syncthreads();
    #pragma unroll
    for (int m = 0; m < 24; m++) pbs[i][sub + m * 16] = f2b(pv_[m]);
    __syncthreads();

    f32x4 oacc; oacc[0] = 0.f; oacc[1] = 0.f; oacc[2] = 0.f; oacc[3] = 0.f;
    for (int jt = 0; jt < 6; jt++) {
        #pragma unroll
        for (int m = 0; m < 2; m++) {
            int g2 = t + m * 256;
            int r = g2 >> 3, c = (g2 & 7) * 8;
            *(int4*)&kvsh[r][c] = *(const int4*)&vp[(size_t)r * S + jt * 64 + c];
        }
        __syncthreads();
        #pragma unroll
        for (int kk = 0; kk < 2; kk++) {
            bf16x8 pa = *(const bf16x8*)&pbs[lane & 15][jt * 64 + kk * 32 + (lane >> 4) * 8];
            bf16x8 bb = *(const bf16x8*)&kvsh[w * 16 + (lane & 15)][kk * 32 + (lane >> 4) * 8];
            oacc = __builtin_amdgcn_mfma_f32_16x16x32_bf16(pa, bb, oacc, 0, 0, 0);
        }
        __syncthreads();
    }
    #pragma unroll
    for (int reg = 0; reg < 4; reg++) {
        int row = (lane >> 4) * 4 + reg;
        int d = w * 16 + (lane & 15);
        float v = oacc[reg] * invs[row];
        aob[((size_t)(b * S + i0 + row)) * D + h * HD + d] = f2b(v);
    }
}

// ---------------- confidence + coords assembly ----------------
__global__ __launch_bounds__(256) void k_conf(const float* __restrict__ hc,
        const float* __restrict__ Wc2, const float* __restrict__ bc2,
        const float* __restrict__ part, const float* __restrict__ bb2,
        float* __restrict__ out) {
    const int wv = threadIdx.x >> 6, lane = threadIdx.x & 63;
    const int row = blockIdx.x * 4 + wv;
    const float* hr = hc + (size_t)row * 256;
    float p = 0.f;
    #pragma unroll
    for (int m = 0; m < 4; m++) p += hr[m * 64 + lane] * Wc2[m * 64 + lane];
    #pragma unroll
    for (int m = 32; m; m >>= 1) p += __shfl_xor(p, m);
    if (lane == 0) out[B * S * 3 + row] = 1.f / (1.f + __expf(-(p + bc2[0])));
    int ci = blockIdx.x * 12 + threadIdx.x;
    if (threadIdx.x < 12) {
        int r = ci / 3, c = ci - r * 3;
        float s = 8.f * bb2[c];
        #pragma unroll
        for (int nb = 0; nb < NSLAB; nb++) s += part[((size_t)nb * BS + r) * 3 + c];
        out[ci] = s;
    }
}

extern "C" void kernel_launch(void* const* d_in, const int* in_sizes, int n_in,
                              void* d_out, int out_size, void* d_ws, size_t ws_size,
                              hipStream_t stream) {
    const float* msa = (const float*)d_in[0];
    const float* pair = (const float*)d_in[1];
    const float* Wq = (const float*)d_in[2];
    const float* bq = (const float*)d_in[3];
    const float* Wk = (const float*)d_in[4];
    const float* bk = (const float*)d_in[5];
    const float* Wv = (const float*)d_in[6];
    const float* bv = (const float*)d_in[7];
    const float* Wpb = (const float*)d_in[8];
    const float* bpb = (const float*)d_in[9];
    const float* Wo = (const float*)d_in[10];
    const float* bo = (const float*)d_in[11];
    const float* Wb1 = (const float*)d_in[12];
    const float* bb1 = (const float*)d_in[13];
    const float* Wb2 = (const float*)d_in[14];
    const float* bb2 = (const float*)d_in[15];
    const float* Wc1 = (const float*)d_in[16];
    const float* bc1 = (const float*)d_in[17];
    const float* Wc2 = (const float*)d_in[18];
    const float* bc2 = (const float*)d_in[19];

    char* base = (char*)d_ws;
    float* x    = (float*)base;            base += (size_t)XN * 4;
    float* hc   = (float*)base;            base += (size_t)BS * 256 * 4;
    float* part = (float*)base;            base += (size_t)NSLAB * BS * 3 * 4;
    unsigned short* xb  = (unsigned short*)base;  base += (size_t)XN * 2;
    unsigned short* aob = (unsigned short*)base;  base += (size_t)XN * 2;
    unsigned short* qbb = (unsigned short*)base;  base += (size_t)XN * 2;
    unsigned short* kbb = (unsigned short*)base;  base += (size_t)XN * 2;
    unsigned short* vtb = (unsigned short*)base;  base += (size_t)XN * 2;
    unsigned short* wt  = (unsigned short*)base;  base += (size_t)34 * DD * 2;
    unsigned short* biasb = (unsigned short*)base;

    k_prep<<<dim3(8, 8, 34), 256, 0, stream>>>(Wq, Wk, Wv, Wo, Wb1, Wc1, wt);
    k_init<<<dim3(1536), 256, 0, stream>>>(msa, x, xb, part);
    k_biasm<<<dim3(6, S, B), 256, 0, stream>>>(pair, Wpb, bpb, biasb);

    for (int l = 0; l < L; ++l) {
        k_phaseA<<<dim3(16, 24, l == 0 ? 3 : 4), 256, 0, stream>>>(xb, wt,
            bq, bk, bv, qbb, kbb, vtb, bb1, Wb2, part, l);
        k_attnm<<<dim3(S / 16, H, B), 256, 0, stream>>>(qbb, kbb, vtb,
            biasb + (size_t)l * BHSS, aob);
        k_wo<<<dim3(16, 24), 256, 0, stream>>>(aob, wt, bo, x, xb, l);
    }

    k_final<<<dim3(16, 24, 2), 256, 0, stream>>>(xb, wt, bb1, Wb2, part, bc1, hc);
    k_conf<<<dim3(BS / 4), 256, 0, stream>>>(hc, Wc2, bc2, part, bb2, (float*)d_out);
}

// Round 8
// 252.676 us; speedup vs baseline: 7.7079x; 1.0591x over previous
//
#include <hip/hip_runtime.h>
#include <math.h>

#define L 8
#define D 512
#define DD (D*D)
#define P 128
#define H 8
#define HD 64
#define B 2
#define NS 4
#define S 384
#define BS (B*S)                     // 768
#define XN (BS*D)                    // 393216
#define SS ((size_t)S*S)             // 147456
#define BHSS ((size_t)B*H*S*S)       // 2359296
#define NSLAB 32                     // part slabs: 16 n-blocks x 2 wc

typedef short bf16x8 __attribute__((ext_vector_type(8)));
typedef float f32x4 __attribute__((ext_vector_type(4)));

__device__ __forceinline__ unsigned short f2b(float f) {
    unsigned u = __float_as_uint(f);
    unsigned r = (u + 0x7FFF + ((u >> 16) & 1)) >> 16;
    return (unsigned short)r;
}
__device__ __forceinline__ float b2f(unsigned short u) {
    return __uint_as_float(((unsigned)u) << 16);
}

// ---------------- init: x = msa[:,0] (f32 + bf16), part = 0 ----------------
__global__ __launch_bounds__(256) void k_init(const float* __restrict__ msa,
                                              float* __restrict__ x,
                                              unsigned short* __restrict__ xb,
                                              float* __restrict__ part) {
    int idx = blockIdx.x * 256 + threadIdx.x;
    if (idx < XN) {
        int b = idx / (S * D);
        int rem = idx - b * (S * D);
        float v = msa[(size_t)b * NS * S * D + rem];
        x[idx] = v;
        xb[idx] = f2b(v);
    }
    if (idx < NSLAB * BS * 3) part[idx] = 0.f;
}

// ---------------- weight prep: transpose+convert to bf16 [N][K] ----------------
// z: 0-7 Wq[l], 8-15 Wk, 16-23 Wv, 24-31 Wo, 32 Wb1, 33 Wc1 (N=256)
__global__ __launch_bounds__(256) void k_prep(const float* __restrict__ Wq,
        const float* __restrict__ Wk, const float* __restrict__ Wv,
        const float* __restrict__ Wo, const float* __restrict__ Wb1,
        const float* __restrict__ Wc1, unsigned short* __restrict__ wt) {
    __shared__ float ts[64][65];
    const int z = blockIdx.z;
    const float* src; int N = 512;
    if (z < 8)       src = Wq + (size_t)z * DD;
    else if (z < 16) src = Wk + (size_t)(z - 8) * DD;
    else if (z < 24) src = Wv + (size_t)(z - 16) * DD;
    else if (z < 32) src = Wo + (size_t)(z - 24) * DD;
    else if (z == 32) src = Wb1;
    else { src = Wc1; N = 256; }
    unsigned short* dst = wt + (size_t)z * DD;

    const int n0 = blockIdx.x * 64, k0 = blockIdx.y * 64;
    if (n0 >= N) return;
    const int t = threadIdx.x;
    #pragma unroll
    for (int m = 0; m < 16; m++) {
        int f = t + m * 256;
        int r = f >> 6, c = f & 63;
        ts[r][c] = src[(size_t)(k0 + r) * N + n0 + c];
    }
    __syncthreads();
    #pragma unroll
    for (int m = 0; m < 4; m++) {
        int o4 = t + m * 256;
        int nr = o4 >> 4, k4 = o4 & 15;
        ushort4 pk;
        pk.x = f2b(ts[k4 * 4 + 0][nr]);
        pk.y = f2b(ts[k4 * 4 + 1][nr]);
        pk.z = f2b(ts[k4 * 4 + 2][nr]);
        pk.w = f2b(ts[k4 * 4 + 3][nr]);
        *(ushort4*)&dst[(size_t)(n0 + nr) * 512 + k0 + k4 * 4] = pk;
    }
}

// ---------------- pair bias via MFMA: bias[l,b,h,i,j] (bf16 out) ----------------
__global__ __launch_bounds__(256) void k_biasm(const float* __restrict__ pair,
        const float* __restrict__ Wpb, const float* __restrict__ bpb,
        unsigned short* __restrict__ bias) {
    __shared__ unsigned short Ws[64][136];
    __shared__ unsigned short Ps[64][136];
    const int t = threadIdx.x;
    const int lane = t & 63, w = t >> 6;
    const int jt = blockIdx.x, i = blockIdx.y, b = blockIdx.z;

    #pragma unroll
    for (int m = 0; m < 8; m++) {
        int f = (t + m * 256) * 4;
        float4 wv = *(const float4*)&Wpb[f];
        int l = f >> 10, rem = f & 1023;
        int k = rem >> 3, h = rem & 7;
        int lh = (l << 3) | h;
        Ws[lh + 0][k] = f2b(wv.x);
        Ws[lh + 1][k] = f2b(wv.y);
        Ws[lh + 2][k] = f2b(wv.z);
        Ws[lh + 3][k] = f2b(wv.w);
    }
    const float* prow = pair + (((size_t)b * S + i) * S + jt * 64) * P;
    #pragma unroll
    for (int m = 0; m < 8; m++) {
        int f = (t + m * 256) * 4;
        int r = f >> 7, c = f & 127;
        float4 pv = *(const float4*)&prow[f];
        ushort4 u;
        u.x = f2b(pv.x); u.y = f2b(pv.y); u.z = f2b(pv.z); u.w = f2b(pv.w);
        *(ushort4*)&Ps[r][c] = u;
    }
    __syncthreads();

    f32x4 acc[4];
    #pragma unroll
    for (int mi = 0; mi < 4; mi++) { acc[mi][0] = 0.f; acc[mi][1] = 0.f; acc[mi][2] = 0.f; acc[mi][3] = 0.f; }
    #pragma unroll
    for (int ks = 0; ks < 4; ks++) {
        bf16x8 bv = *(const bf16x8*)&Ps[w * 16 + (lane & 15)][ks * 32 + (lane >> 4) * 8];
        #pragma unroll
        for (int mi = 0; mi < 4; mi++) {
            bf16x8 av = *(const bf16x8*)&Ws[mi * 16 + (lane & 15)][ks * 32 + (lane >> 4) * 8];
            acc[mi] = __builtin_amdgcn_mfma_f32_16x16x32_bf16(av, bv, acc[mi], 0, 0, 0);
        }
    }
    const int j = jt * 64 + w * 16 + (lane & 15);
    #pragma unroll
    for (int mi = 0; mi < 4; mi++)
        #pragma unroll
        for (int reg = 0; reg < 4; reg++) {
            int lh = mi * 16 + (lane >> 4) * 4 + reg;
            float v = acc[mi][reg] + bpb[lh];
            size_t plane = ((size_t)(lh >> 3) * B + b) * H + (lh & 7);
            bias[plane * SS + (size_t)i * S + j] = f2b(v);
        }
}

// ================= 32x32-tile GEMM core, double-buffered LDS (1 barrier/K-step) =================
// per wave: one 16x16 output tile; wr=row-half, wc=col-half; As/Bs[2][32][72]
#define GEMM32_CORE(Abase, Wbase)                                              \
    f32x4 acc; acc[0] = 0.f; acc[1] = 0.f; acc[2] = 0.f; acc[3] = 0.f;         \
    {                                                                          \
        const unsigned short* pa = &(Abase)[(size_t)(m0 + sr) * 512 + scc];    \
        const unsigned short* pb = &(Wbase)[(size_t)(n0 + sr) * 512 + scc];    \
        int4 ra = *(const int4*)pa;                                            \
        int4 rb = *(const int4*)pb;                                            \
        *(int4*)&As[0][sr][scc] = ra;                                          \
        *(int4*)&Bs[0][sr][scc] = rb;                                          \
        __syncthreads();                                                       \
        int cur = 0;                                                           \
        for (int kt = 0; kt < 512; kt += 64) {                                 \
            if (kt + 64 < 512) {                                               \
                ra = *(const int4*)(pa + kt + 64);                             \
                rb = *(const int4*)(pb + kt + 64);                             \
            }                                                                  \
            _Pragma("unroll")                                                  \
            for (int kk = 0; kk < 2; kk++) {                                   \
                bf16x8 a = *(const bf16x8*)&As[cur][wr * 16 + (lane & 15)][kk * 32 + (lane >> 4) * 8]; \
                bf16x8 bb = *(const bf16x8*)&Bs[cur][wc * 16 + (lane & 15)][kk * 32 + (lane >> 4) * 8]; \
                acc = __builtin_amdgcn_mfma_f32_16x16x32_bf16(a, bb, acc, 0, 0, 0); \
            }                                                                  \
            if (kt + 64 < 512) {                                               \
                *(int4*)&As[cur ^ 1][sr][scc] = ra;                            \
                *(int4*)&Bs[cur ^ 1][sr][scc] = rb;                            \
            }                                                                  \
            __syncthreads();                                                   \
            cur ^= 1;                                                          \
        }                                                                      \
    }

// ---------------- phase A: z=0,1,2 -> Q,K,V projections; z=3 -> Wb1(prev layer) ----------------
__global__ __launch_bounds__(256) void k_phaseA(const unsigned short* __restrict__ xb,
        const unsigned short* __restrict__ wt,
        const float* __restrict__ bq, const float* __restrict__ bk, const float* __restrict__ bv,
        unsigned short* __restrict__ qbb, unsigned short* __restrict__ kbb,
        unsigned short* __restrict__ vtb,
        const float* __restrict__ bb1, const float* __restrict__ Wb2g,
        float* __restrict__ part, int l) {
    __shared__ unsigned short As[2][32][72];
    __shared__ unsigned short Bs[2][32][72];
    const int t = threadIdx.x, lane = t & 63;
    const int w = t >> 6, wr = w >> 1, wc = w & 1;
    const int z = blockIdx.z;
    const int m0 = blockIdx.y * 32, n0 = blockIdx.x * 32;
    const int sr = t >> 3, scc = (t & 7) * 8;

    const unsigned short* Wt;
    const float* bias;
    if (z == 0)      { Wt = wt + (size_t)l * DD;        bias = bq + l * D; }
    else if (z == 1) { Wt = wt + (size_t)(8 + l) * DD;  bias = bk + l * D; }
    else if (z == 2) { Wt = wt + (size_t)(16 + l) * DD; bias = bv + l * D; }
    else             { Wt = wt + (size_t)32 * DD;       bias = bb1; }

    GEMM32_CORE(xb, Wt)

    const int col = n0 + wc * 16 + (lane & 15);
    const float bcol = bias[col];
    if (z < 3) {
        unsigned short* out = (z == 0) ? qbb : (z == 1) ? kbb : vtb;
        const int h = col >> 6, d = col & 63;
        #pragma unroll
        for (int reg = 0; reg < 4; reg++) {
            int row = m0 + wr * 16 + (lane >> 4) * 4 + reg;
            int b = row / S, i = row - b * S;
            float v = acc[reg] + bcol;
            if (z < 2) out[(((size_t)b * H + h) * S + i) * HD + d] = f2b(v);
            else       out[(((size_t)b * H + h) * HD + d) * S + i] = f2b(v);
        }
    } else {
        const float w20 = Wb2g[col * 6 + 0];
        const float w21 = Wb2g[col * 6 + 1];
        const float w22 = Wb2g[col * 6 + 2];
        #pragma unroll
        for (int reg = 0; reg < 4; reg++) {
            float v = fmaxf(acc[reg] + bcol, 0.f);
            float p0 = v * w20, p1 = v * w21, p2 = v * w22;
            #pragma unroll
            for (int m = 1; m < 16; m <<= 1) {
                p0 += __shfl_xor(p0, m);
                p1 += __shfl_xor(p1, m);
                p2 += __shfl_xor(p2, m);
            }
            if ((lane & 15) == 0) {
                int row = m0 + wr * 16 + (lane >> 4) * 4 + reg;
                float* pp = &part[((size_t)(blockIdx.x * 2 + wc) * BS + row) * 3];
                pp[0] += p0; pp[1] += p1; pp[2] += p2;
            }
        }
    }
}

// ---------------- Wo GEMM + residual -> x (f32) and xb (bf16) ----------------
__global__ __launch_bounds__(256) void k_wo(const unsigned short* __restrict__ aob,
        const unsigned short* __restrict__ wt, const float* __restrict__ bo,
        float* __restrict__ x, unsigned short* __restrict__ xb, int l) {
    __shared__ unsigned short As[2][32][72];
    __shared__ unsigned short Bs[2][32][72];
    const int t = threadIdx.x, lane = t & 63;
    const int w = t >> 6, wr = w >> 1, wc = w & 1;
    const int m0 = blockIdx.y * 32, n0 = blockIdx.x * 32;
    const int sr = t >> 3, scc = (t & 7) * 8;
    const unsigned short* Wt = wt + (size_t)(24 + l) * DD;

    GEMM32_CORE(aob, Wt)

    const int col = n0 + wc * 16 + (lane & 15);
    const float bcol = bo[l * D + col];
    #pragma unroll
    for (int reg = 0; reg < 4; reg++) {
        int row = m0 + wr * 16 + (lane >> 4) * 4 + reg;
        float v = acc[reg] + bcol + x[(size_t)row * D + col];
        x[(size_t)row * D + col] = v;
        xb[(size_t)row * D + col] = f2b(v);
    }
}

// ---------------- final: z=0 -> Wb1(L-1) coords partial; z=1 -> Wc1 relu -> hc ----------------
__global__ __launch_bounds__(256) void k_final(const unsigned short* __restrict__ xb,
        const unsigned short* __restrict__ wt,
        const float* __restrict__ bb1, const float* __restrict__ Wb2g, float* __restrict__ part,
        const float* __restrict__ bc1, float* __restrict__ hc) {
    __shared__ unsigned short As[2][32][72];
    __shared__ unsigned short Bs[2][32][72];
    const int t = threadIdx.x, lane = t & 63;
    const int w = t >> 6, wr = w >> 1, wc = w & 1;
    const int z = blockIdx.z;
    if (z == 1 && blockIdx.x >= 8) return;
    const int m0 = blockIdx.y * 32, n0 = blockIdx.x * 32;
    const int sr = t >> 3, scc = (t & 7) * 8;
    const unsigned short* Wt = (z == 0) ? wt + (size_t)32 * DD : wt + (size_t)33 * DD;

    GEMM32_CORE(xb, Wt)

    const int col = n0 + wc * 16 + (lane & 15);
    if (z == 0) {
        const float bcol = bb1[col];
        const float w20 = Wb2g[col * 6 + 0];
        const float w21 = Wb2g[col * 6 + 1];
        const float w22 = Wb2g[col * 6 + 2];
        #pragma unroll
        for (int reg = 0; reg < 4; reg++) {
            float v = fmaxf(acc[reg] + bcol, 0.f);
            float p0 = v * w20, p1 = v * w21, p2 = v * w22;
            #pragma unroll
            for (int m = 1; m < 16; m <<= 1) {
                p0 += __shfl_xor(p0, m);
                p1 += __shfl_xor(p1, m);
                p2 += __shfl_xor(p2, m);
            }
            if ((lane & 15) == 0) {
                int row = m0 + wr * 16 + (lane >> 4) * 4 + reg;
                float* pp = &part[((size_t)(blockIdx.x * 2 + wc) * BS + row) * 3];
                pp[0] += p0; pp[1] += p1; pp[2] += p2;
            }
        }
    } else {
        const float bcol = bc1[col];
        #pragma unroll
        for (int reg = 0; reg < 4; reg++) {
            int row = m0 + wr * 16 + (lane >> 4) * 4 + reg;
            hc[(size_t)row * 256 + col] = fmaxf(acc[reg] + bcol, 0.f);
        }
    }
}

// ---------------- MFMA flash attention, double-buffered K/V staging ----------------
__global__ __launch_bounds__(256) void k_attnm(const unsigned short* __restrict__ qb,
        const unsigned short* __restrict__ kb, const unsigned short* __restrict__ vt,
        const unsigned short* __restrict__ biasL, unsigned short* __restrict__ aob) {
    __shared__ unsigned short qs[16][72];
    __shared__ unsigned short kv[2][64][72];
    __shared__ float scs[16][392];
    __shared__ unsigned short pbs[16][392];
    __shared__ float invs[16];

    const int t = threadIdx.x, lane = t & 63, w = t >> 6;
    const int i0 = blockIdx.x * 16;
    const int h = blockIdx.y, b = blockIdx.z;
    const size_t bh = (size_t)b * H + h;
    const unsigned short* qp = qb + (bh * S + i0) * HD;
    const unsigned short* kp = kb + bh * S * HD;
    const unsigned short* vp = vt + bh * HD * S;
    const unsigned short* bp = biasL + bh * SS + (size_t)i0 * S;

    const int str = t >> 3, stc = (t & 7) * 8;   // 64x64 staging: rows str/str+32

    // prologue: stage Q (16x64), bias (16x384), K tile 0
    if (t < 128) {
        int r = t >> 3, c = (t & 7) * 8;
        *(int4*)&qs[r][c] = *(const int4*)&qp[r * HD + c];
    }
    #pragma unroll
    for (int m = 0; m < 3; m++) {
        int f = t + m * 256;
        int r = f / 48, c = (f % 48) * 8;
        *(int4*)&pbs[r][c] = *(const int4*)&bp[(size_t)r * S + c];
    }
    *(int4*)&kv[0][str][stc]      = *(const int4*)&kp[(size_t)str * HD + stc];
    *(int4*)&kv[0][32 + str][stc] = *(const int4*)&kp[(size_t)(32 + str) * HD + stc];
    __syncthreads();

    bf16x8 qa0 = *(const bf16x8*)&qs[lane & 15][(lane >> 4) * 8];
    bf16x8 qa1 = *(const bf16x8*)&qs[lane & 15][32 + (lane >> 4) * 8];

    // ---- QK^T * scale + bias -> scs (dbuf: 1 barrier/tile) ----
    int cur = 0;
    for (int jt = 0; jt < 6; jt++) {
        int4 r0, r1;
        if (jt < 5) {
            r0 = *(const int4*)&kp[(size_t)((jt + 1) * 64 + str) * HD + stc];
            r1 = *(const int4*)&kp[(size_t)((jt + 1) * 64 + 32 + str) * HD + stc];
        }
        f32x4 acc; acc[0] = 0.f; acc[1] = 0.f; acc[2] = 0.f; acc[3] = 0.f;
        bf16x8 kb0 = *(const bf16x8*)&kv[cur][w * 16 + (lane & 15)][(lane >> 4) * 8];
        bf16x8 kb1 = *(const bf16x8*)&kv[cur][w * 16 + (lane & 15)][32 + (lane >> 4) * 8];
        acc = __builtin_amdgcn_mfma_f32_16x16x32_bf16(qa0, kb0, acc, 0, 0, 0);
        acc = __builtin_amdgcn_mfma_f32_16x16x32_bf16(qa1, kb1, acc, 0, 0, 0);
        const int col = jt * 64 + w * 16 + (lane & 15);
        #pragma unroll
        for (int reg = 0; reg < 4; reg++) {
            int row = (lane >> 4) * 4 + reg;
            scs[row][col] = acc[reg] * 0.125f + b2f(pbs[row][col]);
        }
        if (jt < 5) {
            *(int4*)&kv[cur ^ 1][str][stc]      = r0;
            *(int4*)&kv[cur ^ 1][32 + str][stc] = r1;
        }
        __syncthreads();
        cur ^= 1;
    }

    // ---- softmax (V tile 0 prefetch overlapped) ----
    int4 v0 = *(const int4*)&vp[(size_t)str * S + stc];
    int4 v1 = *(const int4*)&vp[(size_t)(32 + str) * S + stc];
    const int i = t >> 4, sub = t & 15;
    float mx = -1e30f;
    #pragma unroll
    for (int m = 0; m < 24; m++) mx = fmaxf(mx, scs[i][sub + m * 16]);
    #pragma unroll
    for (int m = 1; m < 16; m <<= 1) mx = fmaxf(mx, __shfl_xor(mx, m));
    float pv_[24];
    float sum = 0.f;
    #pragma unroll
    for (int m = 0; m < 24; m++) {
        float p = __expf(scs[i][sub + m * 16] - mx);
        pv_[m] = p;
        sum += p;
    }
    #pragma unroll
    for (int m = 1; m < 16; m <<= 1) sum += __shfl_xor(sum, m);
    if (sub == 0) invs[i] = 1.f / sum;
    #pragma unroll
    for (int m = 0; m < 24; m++) pbs[i][sub + m * 16] = f2b(pv_[m]);
    *(int4*)&kv[0][str][stc]      = v0;
    *(int4*)&kv[0][32 + str][stc] = v1;
    __syncthreads();

    // ---- PV (dbuf) ----
    f32x4 oacc; oacc[0] = 0.f; oacc[1] = 0.f; oacc[2] = 0.f; oacc[3] = 0.f;
    int vc = 0;
    for (int jt = 0; jt < 6; jt++) {
        int4 w0, w1;
        if (jt < 5) {
            w0 = *(const int4*)&vp[(size_t)str * S + (jt + 1) * 64 + stc];
            w1 = *(const int4*)&vp[(size_t)(32 + str) * S + (jt + 1) * 64 + stc];
        }
        #pragma unroll
        for (int kk = 0; kk < 2; kk++) {
            bf16x8 pa = *(const bf16x8*)&pbs[lane & 15][jt * 64 + kk * 32 + (lane >> 4) * 8];
            bf16x8 bb = *(const bf16x8*)&kv[vc][w * 16 + (lane & 15)][kk * 32 + (lane >> 4) * 8];
            oacc = __builtin_amdgcn_mfma_f32_16x16x32_bf16(pa, bb, oacc, 0, 0, 0);
        }
        if (jt < 5) {
            *(int4*)&kv[vc ^ 1][str][stc]      = w0;
            *(int4*)&kv[vc ^ 1][32 + str][stc] = w1;
        }
        __syncthreads();
        vc ^= 1;
    }
    #pragma unroll
    for (int reg = 0; reg < 4; reg++) {
        int row = (lane >> 4) * 4 + reg;
        int d = w * 16 + (lane & 15);
        float v = oacc[reg] * invs[row];
        aob[((size_t)(b * S + i0 + row)) * D + h * HD + d] = f2b(v);
    }
}

// ---------------- confidence + coords assembly ----------------
__global__ __launch_bounds__(256) void k_conf(const float* __restrict__ hc,
        const float* __restrict__ Wc2, const float* __restrict__ bc2,
        const float* __restrict__ part, const float* __restrict__ bb2,
        float* __restrict__ out) {
    const int wv = threadIdx.x >> 6, lane = threadIdx.x & 63;
    const int row = blockIdx.x * 4 + wv;
    const float* hr = hc + (size_t)row * 256;
    float p = 0.f;
    #pragma unroll
    for (int m = 0; m < 4; m++) p += hr[m * 64 + lane] * Wc2[m * 64 + lane];
    #pragma unroll
    for (int m = 32; m; m >>= 1) p += __shfl_xor(p, m);
    if (lane == 0) out[B * S * 3 + row] = 1.f / (1.f + __expf(-(p + bc2[0])));
    int ci = blockIdx.x * 12 + threadIdx.x;
    if (threadIdx.x < 12) {
        int r = ci / 3, c = ci - r * 3;
        float s = 8.f * bb2[c];
        #pragma unroll
        for (int nb = 0; nb < NSLAB; nb++) s += part[((size_t)nb * BS + r) * 3 + c];
        out[ci] = s;
    }
}

extern "C" void kernel_launch(void* const* d_in, const int* in_sizes, int n_in,
                              void* d_out, int out_size, void* d_ws, size_t ws_size,
                              hipStream_t stream) {
    const float* msa = (const float*)d_in[0];
    const float* pair = (const float*)d_in[1];
    const float* Wq = (const float*)d_in[2];
    const float* bq = (const float*)d_in[3];
    const float* Wk = (const float*)d_in[4];
    const float* bk = (const float*)d_in[5];
    const float* Wv = (const float*)d_in[6];
    const float* bv = (const float*)d_in[7];
    const float* Wpb = (const float*)d_in[8];
    const float* bpb = (const float*)d_in[9];
    const float* Wo = (const float*)d_in[10];
    const float* bo = (const float*)d_in[11];
    const float* Wb1 = (const float*)d_in[12];
    const float* bb1 = (const float*)d_in[13];
    const float* Wb2 = (const float*)d_in[14];
    const float* bb2 = (const float*)d_in[15];
    const float* Wc1 = (const float*)d_in[16];
    const float* bc1 = (const float*)d_in[17];
    const float* Wc2 = (const float*)d_in[18];
    const float* bc2 = (const float*)d_in[19];

    char* base = (char*)d_ws;
    float* x    = (float*)base;            base += (size_t)XN * 4;
    float* hc   = (float*)base;            base += (size_t)BS * 256 * 4;
    float* part = (float*)base;            base += (size_t)NSLAB * BS * 3 * 4;
    unsigned short* xb  = (unsigned short*)base;  base += (size_t)XN * 2;
    unsigned short* aob = (unsigned short*)base;  base += (size_t)XN * 2;
    unsigned short* qbb = (unsigned short*)base;  base += (size_t)XN * 2;
    unsigned short* kbb = (unsigned short*)base;  base += (size_t)XN * 2;
    unsigned short* vtb = (unsigned short*)base;  base += (size_t)XN * 2;
    unsigned short* wt  = (unsigned short*)base;  base += (size_t)34 * DD * 2;
    unsigned short* biasb = (unsigned short*)base;

    k_prep<<<dim3(8, 8, 34), 256, 0, stream>>>(Wq, Wk, Wv, Wo, Wb1, Wc1, wt);
    k_init<<<dim3(1536), 256, 0, stream>>>(msa, x, xb, part);
    k_biasm<<<dim3(6, S, B), 256, 0, stream>>>(pair, Wpb, bpb, biasb);

    for (int l = 0; l < L; ++l) {
        k_phaseA<<<dim3(16, 24, l == 0 ? 3 : 4), 256, 0, stream>>>(xb, wt,
            bq, bk, bv, qbb, kbb, vtb, bb1, Wb2, part, l);
        k_attnm<<<dim3(S / 16, H, B), 256, 0, stream>>>(qbb, kbb, vtb,
            biasb + (size_t)l * BHSS, aob);
        k_wo<<<dim3(16, 24), 256, 0, stream>>>(aob, wt, bo, x, xb, l);
    }

    k_final<<<dim3(16, 24, 2), 256, 0, stream>>>(xb, wt, bb1, Wb2, part, bc1, hc);
    k_conf<<<dim3(BS / 4), 256, 0, stream>>>(hc, Wc2, bc2, part, bb2, (float*)d_out);
}